// Round 1
// baseline (387.202 us; speedup 1.0000x reference)
//
#include <hip/hip_runtime.h>

#define BB 4
#define CC 256
#define NN 4096
#define DD 64

typedef _Float16 h8_t __attribute__((ext_vector_type(8)));
typedef _Float16 h4_t __attribute__((ext_vector_type(4)));
typedef float fx4 __attribute__((ext_vector_type(4)));

#define MFMA16(a, b, c) __builtin_amdgcn_mfma_f32_16x16x32_f16((a), (b), (c), 0, 0, 0)

// ---------------- K0: cast weights to f16, zero BN accumulators ----------------
__global__ __launch_bounds__(256) void k0_prep(
    const float* __restrict__ wq, const float* __restrict__ wv, const float* __restrict__ wt,
    _Float16* __restrict__ wqH, _Float16* __restrict__ wvH, _Float16* __restrict__ wtH,
    float* __restrict__ bnsum, float* __restrict__ bnsumsq) {
  int i = blockIdx.x * 256 + threadIdx.x;
  int stride = gridDim.x * 256;
  for (int j = i; j < DD * CC; j += stride) wqH[j] = (_Float16)wq[j];
  for (int j = i; j < CC * CC; j += stride) wvH[j] = (_Float16)wv[j];
  for (int j = i; j < CC * CC; j += stride) wtH[j] = (_Float16)wt[j];
  if (i < CC) { bnsum[i] = 0.f; bnsumsq[i] = 0.f; }
}

// ---------------- K1a: transpose-cast x [b][c][n] f32 -> xt [b][n][c] f16 ------
__global__ __launch_bounds__(256) void k1a_transpose(const float* __restrict__ x,
                                                     _Float16* __restrict__ xt) {
  __shared__ float tile[32][33];
  int b = blockIdx.z;
  int c0 = blockIdx.y * 32, n0 = blockIdx.x * 32;
  int t = threadIdx.x;
  int tn = t & 31, tc = t >> 5;
  const float* xb = x + (size_t)b * CC * NN;
#pragma unroll
  for (int i = 0; i < 4; i++) {
    int c = tc + i * 8;
    tile[c][tn] = xb[(size_t)(c0 + c) * NN + n0 + tn];
  }
  __syncthreads();
  _Float16* xtb = xt + (size_t)b * NN * CC;
#pragma unroll
  for (int i = 0; i < 4; i++) {
    int n = tc + i * 8;
    xtb[(size_t)(n0 + n) * CC + c0 + tn] = (_Float16)tile[tn][n];
  }
}

// ---------------- K1b: projections Q = wq@x, V = wv@x + bv (f16 MFMA) ----------
__global__ __launch_bounds__(256) void k1b_proj(
    const _Float16* __restrict__ xt, const _Float16* __restrict__ wqH,
    const _Float16* __restrict__ wvH, const float* __restrict__ bv,
    _Float16* __restrict__ qh, _Float16* __restrict__ vh) {
  int L = blockIdx.x;
  int xcd = L & 7, j = L >> 3;
  int b = xcd >> 1;
  int nB = ((xcd & 1) * 32 + j) * 64;
  int w = threadIdx.x >> 6, lane = threadIdx.x & 63;
  int g = lane >> 4, q = lane & 15;
  int n = nB + w * 16 + q;
  const _Float16* xr = xt + ((size_t)b * NN + n) * CC;
  fx4 accQ[4] = {};
  fx4 accV[16] = {};
  for (int kt = 0; kt < 8; kt++) {
    h8_t bf = *(const h8_t*)(xr + kt * 32 + g * 8);
#pragma unroll
    for (int ot = 0; ot < 4; ot++) {
      h8_t a = *(const h8_t*)(wqH + (size_t)(ot * 16 + q) * CC + kt * 32 + g * 8);
      accQ[ot] = MFMA16(a, bf, accQ[ot]);
    }
#pragma unroll
    for (int ot = 0; ot < 16; ot++) {
      h8_t a = *(const h8_t*)(wvH + (size_t)(ot * 16 + q) * CC + kt * 32 + g * 8);
      accV[ot] = MFMA16(a, bf, accV[ot]);
    }
  }
  _Float16* qr = qh + ((size_t)b * NN + n) * DD;
#pragma unroll
  for (int ot = 0; ot < 4; ot++) {
    h4_t h;
#pragma unroll
    for (int r = 0; r < 4; r++) h[r] = (_Float16)accQ[ot][r];
    *(h4_t*)(qr + ot * 16 + g * 4) = h;
  }
#pragma unroll
  for (int ot = 0; ot < 16; ot++) {
#pragma unroll
    for (int r = 0; r < 4; r++) {
      int o = ot * 16 + g * 4 + r;
      vh[((size_t)b * CC + o) * NN + n] = (_Float16)(accV[ot][r] + bv[o]);
    }
  }
}

// ---------------- K2: row softmax stats (online max/sum over m) ----------------
__global__ __launch_bounds__(512) void k2_rowstats(
    const _Float16* __restrict__ qh, float* __restrict__ rowmax,
    float* __restrict__ rowsuminv) {
  int L = blockIdx.x;
  int xcd = L & 7, j = L >> 3;
  int b = xcd >> 1;
  int nB = ((xcd & 1) * 32 + j) * 64;
  int w = threadIdx.x >> 6, lane = threadIdx.x & 63;
  int g = lane >> 4, q = lane & 15;
  int rt = w & 3, mh = w >> 2;
  const _Float16* qb = qh + (size_t)b * NN * DD;
  int row0 = nB + rt * 16;
  h8_t a0 = *(const h8_t*)(qb + (size_t)(row0 + q) * DD + g * 8);
  h8_t a1 = *(const h8_t*)(qb + (size_t)(row0 + q) * DD + 32 + g * 8);
  float cm[4] = {-1e30f, -1e30f, -1e30f, -1e30f};
  float s[4] = {0.f, 0.f, 0.f, 0.f};
  for (int mt = 0; mt < 128; mt++) {
    int m = mh * 2048 + mt * 16;
    h8_t b0 = *(const h8_t*)(qb + (size_t)(m + q) * DD + g * 8);
    h8_t b1 = *(const h8_t*)(qb + (size_t)(m + q) * DD + 32 + g * 8);
    fx4 e = {};
    e = MFMA16(a0, b0, e);
    e = MFMA16(a1, b1, e);
#pragma unroll
    for (int r = 0; r < 4; r++) {
      float v = e[r];
      if (v <= cm[r]) {
        s[r] += __expf(v - cm[r]);
      } else {
        s[r] = s[r] * __expf(cm[r] - v) + 1.f;
        cm[r] = v;
      }
    }
  }
#pragma unroll
  for (int off = 1; off < 16; off <<= 1) {
#pragma unroll
    for (int r = 0; r < 4; r++) {
      float om = __shfl_xor(cm[r], off);
      float os = __shfl_xor(s[r], off);
      float nm = fmaxf(cm[r], om);
      s[r] = s[r] * __expf(cm[r] - nm) + os * __expf(om - nm);
      cm[r] = nm;
    }
  }
  __shared__ float lmax[8][16], lsum[8][16];
  if (q == 0) {
#pragma unroll
    for (int r = 0; r < 4; r++) { lmax[w][g * 4 + r] = cm[r]; lsum[w][g * 4 + r] = s[r]; }
  }
  __syncthreads();
  if (threadIdx.x < 64) {
    int rt2 = threadIdx.x >> 4, r16 = threadIdx.x & 15;
    float M0 = lmax[rt2][r16], S0 = lsum[rt2][r16];
    float M1 = lmax[rt2 + 4][r16], S1 = lsum[rt2 + 4][r16];
    float M = fmaxf(M0, M1);
    float S = S0 * __expf(M0 - M) + S1 * __expf(M1 - M);
    int row = nB + rt2 * 16 + r16;
    rowmax[b * NN + row] = M;
    rowsuminv[b * NN + row] = 1.f / S;
  }
}

// ---------------- K3: column sums of row-normalized attn -----------------------
__global__ __launch_bounds__(512) void k3_colsum(
    const _Float16* __restrict__ qh, const float* __restrict__ rowmax,
    const float* __restrict__ rowsuminv, float* __restrict__ colsum) {
  int L = blockIdx.x;
  int xcd = L & 7, j = L >> 3;
  int b = xcd >> 1;
  int mB = ((xcd & 1) * 32 + j) * 64;
  int w = threadIdx.x >> 6, lane = threadIdx.x & 63;
  int g = lane >> 4, q = lane & 15;
  int ct = w & 3, nh = w >> 2;
  const _Float16* qb = qh + (size_t)b * NN * DD;
  int col0 = mB + ct * 16;
  h8_t b0 = *(const h8_t*)(qb + (size_t)(col0 + q) * DD + g * 8);
  h8_t b1 = *(const h8_t*)(qb + (size_t)(col0 + q) * DD + 32 + g * 8);
  const float* rm = rowmax + b * NN;
  const float* ri = rowsuminv + b * NN;
  float acc = 0.f;
  for (int nt = 0; nt < 128; nt++) {
    int n = nh * 2048 + nt * 16;
    h8_t a0 = *(const h8_t*)(qb + (size_t)(n + q) * DD + g * 8);
    h8_t a1 = *(const h8_t*)(qb + (size_t)(n + q) * DD + 32 + g * 8);
    fx4 e = {};
    e = MFMA16(a0, b0, e);
    e = MFMA16(a1, b1, e);
#pragma unroll
    for (int r = 0; r < 4; r++) {
      int row = n + g * 4 + r;
      acc += __expf(e[r] - rm[row]) * ri[row];
    }
  }
  acc += __shfl_xor(acc, 16);
  acc += __shfl_xor(acc, 32);
  __shared__ float part[8][16];
  if (lane < 16) part[w][lane] = acc;
  __syncthreads();
  if (threadIdx.x < 64) {
    int ct2 = threadIdx.x >> 4, c16 = threadIdx.x & 15;
    colsum[b * NN + mB + ct2 * 16 + c16] = part[ct2][c16] + part[ct2 + 4][c16];
  }
}

// ---------------- K4: fused P -> x_a -> x_d -> t -> BN partials ----------------
__global__ __launch_bounds__(512) void k4_main(
    const _Float16* __restrict__ qh, const _Float16* __restrict__ vh,
    const _Float16* __restrict__ wtH, const float* __restrict__ rowmax,
    const float* __restrict__ rowsuminv, const float* __restrict__ colsum,
    const float* __restrict__ x, const float* __restrict__ bt,
    _Float16* __restrict__ th, float* __restrict__ bnsum, float* __restrict__ bnsumsq) {
  __shared__ _Float16 Pt[64][136];    // [m][n_local], padded stride
  __shared__ _Float16 xdT[64][264];   // [m][c], padded stride
  int L = blockIdx.x;
  int xcd = L & 7, jj = L >> 3;
  int b = xcd >> 1;
  int mB = ((xcd & 1) * 32 + jj) * 64;
  int w = threadIdx.x >> 6, lane = threadIdx.x & 63;
  int g = lane >> 4, q = lane & 15;
  const _Float16* qb = qh + (size_t)b * NN * DD;
  const float* rm = rowmax + b * NN;
  const float* ri = rowsuminv + b * NN;

  h8_t bq[4][2];
#pragma unroll
  for (int ms = 0; ms < 4; ms++) {
    bq[ms][0] = *(const h8_t*)(qb + (size_t)(mB + ms * 16 + q) * DD + g * 8);
    bq[ms][1] = *(const h8_t*)(qb + (size_t)(mB + ms * 16 + q) * DD + 32 + g * 8);
  }
  fx4 acc[2][4] = {};  // [ct][mt]
  for (int ch = 0; ch < 32; ch++) {
    int nB = ch * 128;
    // step 1: this wave computes P rows [nB+16w, nB+16w+16) x 64 cols
    {
      int arow = nB + 16 * w + q;
      h8_t a0 = *(const h8_t*)(qb + (size_t)arow * DD + g * 8);
      h8_t a1 = *(const h8_t*)(qb + (size_t)arow * DD + 32 + g * 8);
      float rmv[4], riv[4];
#pragma unroll
      for (int r = 0; r < 4; r++) {
        int row = nB + 16 * w + g * 4 + r;
        rmv[r] = rm[row];
        riv[r] = ri[row];
      }
#pragma unroll
      for (int ms = 0; ms < 4; ms++) {
        fx4 e = {};
        e = MFMA16(a0, bq[ms][0], e);
        e = MFMA16(a1, bq[ms][1], e);
        h4_t p;
#pragma unroll
        for (int r = 0; r < 4; r++)
          p[r] = (_Float16)(__expf(e[r] - rmv[r]) * riv[r]);
        *(h4_t*)&Pt[ms * 16 + q][16 * w + g * 4] = p;
      }
    }
    __syncthreads();
    // step 2: acc[c-tile][m-tile] += V[c, n-chunk] @ P[n-chunk, m]
#pragma unroll
    for (int kt = 0; kt < 4; kt++) {
      h8_t bp[4];
#pragma unroll
      for (int mt = 0; mt < 4; mt++)
        bp[mt] = *(const h8_t*)&Pt[mt * 16 + q][kt * 32 + g * 8];
#pragma unroll
      for (int ct = 0; ct < 2; ct++) {
        h8_t av = *(const h8_t*)(vh + ((size_t)b * CC + 32 * w + ct * 16 + q) * NN + nB + kt * 32 + g * 8);
#pragma unroll
        for (int mt = 0; mt < 4; mt++)
          acc[ct][mt] = MFMA16(av, bp[mt], acc[ct][mt]);
      }
    }
    __syncthreads();
  }
  // epilogue: x_a = acc / colsum ; x_d = x - x_a -> xdT (f16)
  float cinv[4];
#pragma unroll
  for (int mt = 0; mt < 4; mt++)
    cinv[mt] = 1.f / (1e-9f + colsum[b * NN + mB + mt * 16 + q]);
#pragma unroll
  for (int ct = 0; ct < 2; ct++) {
#pragma unroll
    for (int mt = 0; mt < 4; mt++) {
      h4_t hd;
#pragma unroll
      for (int r = 0; r < 4; r++) {
        int c = 32 * w + ct * 16 + g * 4 + r;
        int m = mB + mt * 16 + q;
        float xa = acc[ct][mt][r] * cinv[mt];
        float xd = x[((size_t)b * CC + c) * NN + m] - xa;
        hd[r] = (_Float16)xd;
      }
      *(h4_t*)&xdT[mt * 16 + q][32 * w + ct * 16 + g * 4] = hd;
    }
  }
  __syncthreads();
  // t = wt @ x_d + bt (full C contraction from LDS)
  fx4 acct[2][4] = {};
  for (int kt = 0; kt < 8; kt++) {
    h8_t bx[4];
#pragma unroll
    for (int mt = 0; mt < 4; mt++)
      bx[mt] = *(const h8_t*)&xdT[mt * 16 + q][kt * 32 + g * 8];
#pragma unroll
    for (int ot = 0; ot < 2; ot++) {
      h8_t a = *(const h8_t*)(wtH + (size_t)(32 * w + ot * 16 + q) * CC + kt * 32 + g * 8);
#pragma unroll
      for (int mt = 0; mt < 4; mt++)
        acct[ot][mt] = MFMA16(a, bx[mt], acct[ot][mt]);
    }
  }
#pragma unroll
  for (int ot = 0; ot < 2; ot++) {
#pragma unroll
    for (int r = 0; r < 4; r++) {
      int o = 32 * w + ot * 16 + g * 4 + r;
      float btv = bt[o];
      float s1 = 0.f, s2 = 0.f;
#pragma unroll
      for (int mt = 0; mt < 4; mt++) {
        float tv = acct[ot][mt][r] + btv;
        th[((size_t)b * CC + o) * NN + mB + mt * 16 + q] = (_Float16)tv;
        s1 += tv;
        s2 += tv * tv;
      }
#pragma unroll
      for (int off = 1; off < 16; off <<= 1) {
        s1 += __shfl_xor(s1, off);
        s2 += __shfl_xor(s2, off);
      }
      if (q == 0) {
        atomicAdd(&bnsum[o], s1);
        atomicAdd(&bnsumsq[o], s2);
      }
    }
  }
}

// ---------------- K5: BN finalize -> scale/shift per channel -------------------
__global__ __launch_bounds__(256) void k5_bnfinal(
    const float* __restrict__ bnsum, const float* __restrict__ bnsumsq,
    const float* __restrict__ gamma, const float* __restrict__ beta,
    float* __restrict__ bnsc, float* __restrict__ bnsh) {
  int c = threadIdx.x;
  float inv = 1.f / (float)(BB * NN);
  float mean = bnsum[c] * inv;
  float var = bnsumsq[c] * inv - mean * mean;
  float sc = gamma[c] * rsqrtf(var + 1e-5f);
  bnsc[c] = sc;
  bnsh[c] = beta[c] - mean * sc;
}

// ---------------- K6: out = x + relu(scale*t + shift) --------------------------
__global__ __launch_bounds__(256) void k6_final(
    const float* __restrict__ x, const _Float16* __restrict__ th,
    const float* __restrict__ bnsc, const float* __restrict__ bnsh,
    float* __restrict__ out) {
  size_t i = (size_t)blockIdx.x * 256 + threadIdx.x;
  size_t base = i * 8;
  int c = (int)((base >> 12) & 255);
  h8_t t8 = *(const h8_t*)(th + base);
  float sc = bnsc[c], sh = bnsh[c];
  fx4 x0 = *(const fx4*)(x + base);
  fx4 x1 = *(const fx4*)(x + base + 4);
  fx4 o0, o1;
#pragma unroll
  for (int j2 = 0; j2 < 4; j2++) {
    o0[j2] = x0[j2] + fmaxf(0.f, sc * (float)t8[j2] + sh);
    o1[j2] = x1[j2] + fmaxf(0.f, sc * (float)t8[j2 + 4] + sh);
  }
  *(fx4*)(out + base) = o0;
  *(fx4*)(out + base + 4) = o1;
}

extern "C" void kernel_launch(void* const* d_in, const int* in_sizes, int n_in,
                              void* d_out, int out_size, void* d_ws, size_t ws_size,
                              hipStream_t stream) {
  const float* x = (const float*)d_in[0];
  const float* wq = (const float*)d_in[1];
  const float* wv = (const float*)d_in[2];
  const float* bv = (const float*)d_in[3];
  const float* wt = (const float*)d_in[4];
  const float* bt = (const float*)d_in[5];
  const float* gamma = (const float*)d_in[6];
  const float* beta = (const float*)d_in[7];
  char* ws = (char*)d_ws;
  _Float16* qh = (_Float16*)(ws + 0);            // 2 MB
  _Float16* vh = (_Float16*)(ws + 2097152);      // 8 MB
  _Float16* xt = (_Float16*)(ws + 10485760);     // 8 MB
  _Float16* wqH = (_Float16*)(ws + 18874368);    // 32 KB
  _Float16* wvH = (_Float16*)(ws + 18907136);    // 128 KB
  _Float16* wtH = (_Float16*)(ws + 19038208);    // 128 KB
  float* rowmax = (float*)(ws + 19169280);       // 64 KB
  float* rowsuminv = (float*)(ws + 19234816);    // 64 KB
  float* colsum = (float*)(ws + 19300352);       // 64 KB
  float* bnsum = (float*)(ws + 19365888);        // 1 KB
  float* bnsumsq = (float*)(ws + 19366912);      // 1 KB
  float* bnsc = (float*)(ws + 19367936);         // 1 KB
  float* bnsh = (float*)(ws + 19368960);         // 1 KB
  _Float16* th = (_Float16*)(ws + 19369984);     // 8 MB  (total ~26.5 MB)

  hipLaunchKernelGGL(k0_prep, dim3(64), dim3(256), 0, stream,
                     wq, wv, wt, wqH, wvH, wtH, bnsum, bnsumsq);
  hipLaunchKernelGGL(k1a_transpose, dim3(128, 8, 4), dim3(256), 0, stream, x, xt);
  hipLaunchKernelGGL(k1b_proj, dim3(256), dim3(256), 0, stream, xt, wqH, wvH, bv, qh, vh);
  hipLaunchKernelGGL(k2_rowstats, dim3(256), dim3(512), 0, stream, qh, rowmax, rowsuminv);
  hipLaunchKernelGGL(k3_colsum, dim3(256), dim3(512), 0, stream, qh, rowmax, rowsuminv, colsum);
  hipLaunchKernelGGL(k4_main, dim3(256), dim3(512), 0, stream, qh, vh, wtH,
                     rowmax, rowsuminv, colsum, x, bt, th, bnsum, bnsumsq);
  hipLaunchKernelGGL(k5_bnfinal, dim3(1), dim3(256), 0, stream,
                     bnsum, bnsumsq, gamma, beta, bnsc, bnsh);
  hipLaunchKernelGGL(k6_final, dim3(2048), dim3(256), 0, stream,
                     x, th, bnsc, bnsh, (float*)d_out);
}

// Round 2
// 305.036 us; speedup vs baseline: 1.2694x; 1.2694x over previous
//
#include <hip/hip_runtime.h>

#define BB 4
#define CC 256
#define NN 4096
#define DD 64

typedef _Float16 h8_t __attribute__((ext_vector_type(8)));
typedef _Float16 h4_t __attribute__((ext_vector_type(4)));
typedef float fx4 __attribute__((ext_vector_type(4)));

#define MFMA16(a, b, c) __builtin_amdgcn_mfma_f32_16x16x32_f16((a), (b), (c), 0, 0, 0)

// ---------------- K0: cast weights to f16, zero BN accumulators ----------------
__global__ __launch_bounds__(256) void k0_prep(
    const float* __restrict__ wq, const float* __restrict__ wv, const float* __restrict__ wt,
    _Float16* __restrict__ wqH, _Float16* __restrict__ wvH, _Float16* __restrict__ wtH,
    float* __restrict__ bnsum, float* __restrict__ bnsumsq) {
  int i = blockIdx.x * 256 + threadIdx.x;
  int stride = gridDim.x * 256;
  for (int j = i; j < DD * CC; j += stride) wqH[j] = (_Float16)wq[j];
  for (int j = i; j < CC * CC; j += stride) wvH[j] = (_Float16)wv[j];
  for (int j = i; j < CC * CC; j += stride) wtH[j] = (_Float16)wt[j];
  if (i < CC) { bnsum[i] = 0.f; bnsumsq[i] = 0.f; }
}

// ---------------- K1a: transpose-cast x [b][c][n] f32 -> xt [b][n][c] f16 ------
__global__ __launch_bounds__(256) void k1a_transpose(const float* __restrict__ x,
                                                     _Float16* __restrict__ xt) {
  __shared__ float tile[32][33];
  int b = blockIdx.z;
  int c0 = blockIdx.y * 32, n0 = blockIdx.x * 32;
  int t = threadIdx.x;
  int tn = t & 31, tc = t >> 5;
  const float* xb = x + (size_t)b * CC * NN;
#pragma unroll
  for (int i = 0; i < 4; i++) {
    int c = tc + i * 8;
    tile[c][tn] = xb[(size_t)(c0 + c) * NN + n0 + tn];
  }
  __syncthreads();
  _Float16* xtb = xt + (size_t)b * NN * CC;
#pragma unroll
  for (int i = 0; i < 4; i++) {
    int n = tc + i * 8;
    xtb[(size_t)(n0 + n) * CC + c0 + tn] = (_Float16)tile[tn][n];
  }
}

// ---------------- K1b: projections Q = wq@x, V = wv@x + bv (f16 MFMA) ----------
// grid 512 (2 blocks/CU), 256 thr. n-tile 32; waves: w&1 -> n-subtile, w>>1 -> channel half
__global__ __launch_bounds__(256, 2) void k1b_proj(
    const _Float16* __restrict__ xt, const _Float16* __restrict__ wqH,
    const _Float16* __restrict__ wvH, const float* __restrict__ bv,
    _Float16* __restrict__ qh, _Float16* __restrict__ vh) {
  int L = blockIdx.x;
  int xcd = L & 7, j = L >> 3;
  int b = xcd >> 1;
  int nB = ((xcd & 1) * 64 + j) * 32;
  int w = threadIdx.x >> 6, lane = threadIdx.x & 63;
  int g = lane >> 4, q = lane & 15;
  int wsub = w & 1, h = w >> 1;
  int n = nB + wsub * 16 + q;
  const _Float16* xr = xt + ((size_t)b * NN + n) * CC;
  fx4 accQ[4] = {};
  fx4 accV[8] = {};
  for (int kt = 0; kt < 8; kt++) {
    h8_t bf = *(const h8_t*)(xr + kt * 32 + g * 8);
    if (h == 0) {
#pragma unroll
      for (int ot = 0; ot < 4; ot++) {
        h8_t a = *(const h8_t*)(wqH + (size_t)(ot * 16 + q) * CC + kt * 32 + g * 8);
        accQ[ot] = MFMA16(a, bf, accQ[ot]);
      }
    }
#pragma unroll
    for (int ot = 0; ot < 8; ot++) {
      int o16 = h * 8 + ot;
      h8_t a = *(const h8_t*)(wvH + (size_t)(o16 * 16 + q) * CC + kt * 32 + g * 8);
      accV[ot] = MFMA16(a, bf, accV[ot]);
    }
  }
  if (h == 0) {
    _Float16* qr = qh + ((size_t)b * NN + n) * DD;
#pragma unroll
    for (int ot = 0; ot < 4; ot++) {
      h4_t hq;
#pragma unroll
      for (int r = 0; r < 4; r++) hq[r] = (_Float16)accQ[ot][r];
      *(h4_t*)(qr + ot * 16 + g * 4) = hq;
    }
  }
#pragma unroll
  for (int ot = 0; ot < 8; ot++) {
#pragma unroll
    for (int r = 0; r < 4; r++) {
      int o = (h * 8 + ot) * 16 + g * 4 + r;
      vh[((size_t)b * CC + o) * NN + n] = (_Float16)(accV[ot][r] + bv[o]);
    }
  }
}

// ---------------- K2: rowmax (phase 1) + rowsum (phase 2), branchless ----------
__global__ __launch_bounds__(512, 2) void k2_stats(
    const _Float16* __restrict__ qh, float* __restrict__ rowmax,
    float* __restrict__ rowsuminv) {
  __shared__ float redb[8][64];
  __shared__ float rmLDS[64];
  int L = blockIdx.x;
  int xcd = L & 7, j = L >> 3;
  int b = xcd >> 1;
  int mB = ((xcd & 1) * 32 + j) * 64;
  int w = threadIdx.x >> 6, lane = threadIdx.x & 63;
  int g = lane >> 4, q = lane & 15;
  const _Float16* qb = qh + (size_t)b * NN * DD;
  h8_t aq[4][2];
#pragma unroll
  for (int mt = 0; mt < 4; mt++) {
    aq[mt][0] = *(const h8_t*)(qb + (size_t)(mB + mt * 16 + q) * DD + g * 8);
    aq[mt][1] = *(const h8_t*)(qb + (size_t)(mB + mt * 16 + q) * DD + 32 + g * 8);
  }
  // phase 1: max over n
  fx4 rmax[4];
#pragma unroll
  for (int mt = 0; mt < 4; mt++)
#pragma unroll
    for (int r = 0; r < 4; r++) rmax[mt][r] = -1e30f;
  for (int ch = 0; ch < 32; ch++) {
    int n0 = ch * 128 + w * 16;
    h8_t b0 = *(const h8_t*)(qb + (size_t)(n0 + q) * DD + g * 8);
    h8_t b1 = *(const h8_t*)(qb + (size_t)(n0 + q) * DD + 32 + g * 8);
#pragma unroll
    for (int mt = 0; mt < 4; mt++) {
      fx4 e = {};
      e = MFMA16(aq[mt][0], b0, e);
      e = MFMA16(aq[mt][1], b1, e);
#pragma unroll
      for (int r = 0; r < 4; r++) rmax[mt][r] = fmaxf(rmax[mt][r], e[r]);
    }
  }
#pragma unroll
  for (int off = 1; off < 16; off <<= 1)
#pragma unroll
    for (int mt = 0; mt < 4; mt++)
#pragma unroll
      for (int r = 0; r < 4; r++)
        rmax[mt][r] = fmaxf(rmax[mt][r], __shfl_xor(rmax[mt][r], off));
  if (q == 0) {
#pragma unroll
    for (int mt = 0; mt < 4; mt++)
#pragma unroll
      for (int r = 0; r < 4; r++) redb[w][mt * 16 + g * 4 + r] = rmax[mt][r];
  }
  __syncthreads();
  if (threadIdx.x < 64) {
    float M = redb[0][threadIdx.x];
#pragma unroll
    for (int w2 = 1; w2 < 8; w2++) M = fmaxf(M, redb[w2][threadIdx.x]);
    rmLDS[threadIdx.x] = M;
    rowmax[b * NN + mB + threadIdx.x] = M;
  }
  __syncthreads();
  // phase 2: sum of exp(e - rm)
  float rmv[4][4];
#pragma unroll
  for (int mt = 0; mt < 4; mt++)
#pragma unroll
    for (int r = 0; r < 4; r++) rmv[mt][r] = rmLDS[mt * 16 + g * 4 + r];
  fx4 s[4] = {};
  for (int ch = 0; ch < 32; ch++) {
    int n0 = ch * 128 + w * 16;
    h8_t b0 = *(const h8_t*)(qb + (size_t)(n0 + q) * DD + g * 8);
    h8_t b1 = *(const h8_t*)(qb + (size_t)(n0 + q) * DD + 32 + g * 8);
#pragma unroll
    for (int mt = 0; mt < 4; mt++) {
      fx4 e = {};
      e = MFMA16(aq[mt][0], b0, e);
      e = MFMA16(aq[mt][1], b1, e);
#pragma unroll
      for (int r = 0; r < 4; r++) s[mt][r] += __expf(e[r] - rmv[mt][r]);
    }
  }
#pragma unroll
  for (int off = 1; off < 16; off <<= 1)
#pragma unroll
    for (int mt = 0; mt < 4; mt++)
#pragma unroll
      for (int r = 0; r < 4; r++) s[mt][r] += __shfl_xor(s[mt][r], off);
  if (q == 0) {
#pragma unroll
    for (int mt = 0; mt < 4; mt++)
#pragma unroll
      for (int r = 0; r < 4; r++) redb[w][mt * 16 + g * 4 + r] = s[mt][r];
  }
  __syncthreads();
  if (threadIdx.x < 64) {
    float S = redb[0][threadIdx.x];
#pragma unroll
    for (int w2 = 1; w2 < 8; w2++) S += redb[w2][threadIdx.x];
    rowsuminv[b * NN + mB + threadIdx.x] = 1.f / S;
  }
}

// ---------------- K3: colsum[m] = sum_n exp(e[m,n]-rm[n])*ri[n] ----------------
__global__ __launch_bounds__(512, 2) void k3_colsum(
    const _Float16* __restrict__ qh, const float* __restrict__ rowmax,
    const float* __restrict__ rowsuminv, float* __restrict__ colsum) {
  __shared__ float redb[8][64];
  int L = blockIdx.x;
  int xcd = L & 7, j = L >> 3;
  int b = xcd >> 1;
  int mB = ((xcd & 1) * 32 + j) * 64;
  int w = threadIdx.x >> 6, lane = threadIdx.x & 63;
  int g = lane >> 4, q = lane & 15;
  const _Float16* qb = qh + (size_t)b * NN * DD;
  const float* rm = rowmax + b * NN;
  const float* ri = rowsuminv + b * NN;
  h8_t aq[4][2];
#pragma unroll
  for (int mt = 0; mt < 4; mt++) {
    aq[mt][0] = *(const h8_t*)(qb + (size_t)(mB + mt * 16 + q) * DD + g * 8);
    aq[mt][1] = *(const h8_t*)(qb + (size_t)(mB + mt * 16 + q) * DD + 32 + g * 8);
  }
  fx4 colp[4] = {};
  for (int ch = 0; ch < 32; ch++) {
    int n0 = ch * 128 + w * 16;
    h8_t b0 = *(const h8_t*)(qb + (size_t)(n0 + q) * DD + g * 8);
    h8_t b1 = *(const h8_t*)(qb + (size_t)(n0 + q) * DD + 32 + g * 8);
    float rmn = rm[n0 + q];
    float rin = ri[n0 + q];
#pragma unroll
    for (int mt = 0; mt < 4; mt++) {
      fx4 e = {};
      e = MFMA16(aq[mt][0], b0, e);
      e = MFMA16(aq[mt][1], b1, e);
#pragma unroll
      for (int r = 0; r < 4; r++) colp[mt][r] += __expf(e[r] - rmn) * rin;
    }
  }
#pragma unroll
  for (int off = 1; off < 16; off <<= 1)
#pragma unroll
    for (int mt = 0; mt < 4; mt++)
#pragma unroll
      for (int r = 0; r < 4; r++) colp[mt][r] += __shfl_xor(colp[mt][r], off);
  if (q == 0) {
#pragma unroll
    for (int mt = 0; mt < 4; mt++)
#pragma unroll
      for (int r = 0; r < 4; r++) redb[w][mt * 16 + g * 4 + r] = colp[mt][r];
  }
  __syncthreads();
  if (threadIdx.x < 64) {
    float S = redb[0][threadIdx.x];
#pragma unroll
    for (int w2 = 1; w2 < 8; w2++) S += redb[w2][threadIdx.x];
    colsum[b * NN + mB + threadIdx.x] = S;
  }
}

// ---------------- K4: double-buffered P -> x_a -> x_d -> t -> BN ---------------
// P tile [64 m][128 n] f16, XOR-swizzled: phys_idx = (m*128+nl) ^ ((m&7)<<3)
// xdT tile [64 m][256 c] f16, XOR-swizzled: phys_idx = (m*256+c) ^ ((m&7)<<3)
__global__ __launch_bounds__(512, 2) void k4_main(
    const _Float16* __restrict__ qh, const _Float16* __restrict__ vh,
    const _Float16* __restrict__ wtH, const float* __restrict__ rowmax,
    const float* __restrict__ rowsuminv, const float* __restrict__ colsum,
    const float* __restrict__ x, const float* __restrict__ bt,
    _Float16* __restrict__ th, float* __restrict__ bnsum, float* __restrict__ bnsumsq) {
  __shared__ _Float16 Pb[2][64 * 128];
  __shared__ _Float16 xdT[64 * 256];
  int L = blockIdx.x;
  int xcd = L & 7, jj = L >> 3;
  int b = xcd >> 1;
  int mB = ((xcd & 1) * 32 + jj) * 64;
  int w = threadIdx.x >> 6, lane = threadIdx.x & 63;
  int g = lane >> 4, q = lane & 15;
  const _Float16* qb = qh + (size_t)b * NN * DD;
  const float* rm = rowmax + b * NN;
  const float* ri = rowsuminv + b * NN;

  // Q fragments for this block's m-tile (persistent)
  h8_t aq[4][2];
#pragma unroll
  for (int mt = 0; mt < 4; mt++) {
    aq[mt][0] = *(const h8_t*)(qb + (size_t)(mB + mt * 16 + q) * DD + g * 8);
    aq[mt][1] = *(const h8_t*)(qb + (size_t)(mB + mt * 16 + q) * DD + 32 + g * 8);
  }

  // prologue: build P chunk 0
  {
    int n0 = 0 * 128 + w * 16;
    h8_t b0 = *(const h8_t*)(qb + (size_t)(n0 + q) * DD + g * 8);
    h8_t b1 = *(const h8_t*)(qb + (size_t)(n0 + q) * DD + 32 + g * 8);
    float rmn = rm[n0 + q], rin = ri[n0 + q];
    int nl = w * 16 + q;
#pragma unroll
    for (int mt = 0; mt < 4; mt++) {
      fx4 e = {};
      e = MFMA16(aq[mt][0], b0, e);
      e = MFMA16(aq[mt][1], b1, e);
#pragma unroll
      for (int r = 0; r < 4; r++) {
        int m = mt * 16 + 4 * g + r;
        Pb[0][(m * 128 + nl) ^ ((m & 7) << 3)] = (_Float16)(__expf(e[r] - rmn) * rin);
      }
    }
  }
  __syncthreads();

  fx4 acc[2][4] = {};  // [ct][mt]
  int swzq = (q & 7) << 3;
  for (int ch = 0; ch < 32; ch++) {
    int cur = ch & 1;
    int nB = ch * 128;
    // issue next-chunk loads early
    h8_t b0n, b1n;
    float rmn = 0.f, rin = 0.f;
    if (ch < 31) {
      int n0 = (ch + 1) * 128 + w * 16;
      b0n = *(const h8_t*)(qb + (size_t)(n0 + q) * DD + g * 8);
      b1n = *(const h8_t*)(qb + (size_t)(n0 + q) * DD + 32 + g * 8);
      rmn = rm[n0 + q];
      rin = ri[n0 + q];
    }
    // V-GEMM on current P
#pragma unroll
    for (int kt = 0; kt < 4; kt++) {
      h8_t bp[4];
#pragma unroll
      for (int mt = 0; mt < 4; mt++) {
        int m = mt * 16 + q;
        bp[mt] = *(const h8_t*)&Pb[cur][(m * 128 + kt * 32 + g * 8) ^ swzq];
      }
#pragma unroll
      for (int ct = 0; ct < 2; ct++) {
        h8_t av = *(const h8_t*)(vh + ((size_t)b * CC + 32 * w + ct * 16 + q) * NN + nB + kt * 32 + g * 8);
#pragma unroll
        for (int mt = 0; mt < 4; mt++)
          acc[ct][mt] = MFMA16(av, bp[mt], acc[ct][mt]);
      }
    }
    // build next P into other buffer
    if (ch < 31) {
      int nl = w * 16 + q;
#pragma unroll
      for (int mt = 0; mt < 4; mt++) {
        fx4 e = {};
        e = MFMA16(aq[mt][0], b0n, e);
        e = MFMA16(aq[mt][1], b1n, e);
#pragma unroll
        for (int r = 0; r < 4; r++) {
          int m = mt * 16 + 4 * g + r;
          Pb[cur ^ 1][(m * 128 + nl) ^ ((m & 7) << 3)] = (_Float16)(__expf(e[r] - rmn) * rin);
        }
      }
    }
    __syncthreads();
  }

  // epilogue: x_a = acc / colsum ; x_d = x - x_a -> xdT (f16, swizzled)
  float cinv[4];
#pragma unroll
  for (int mt = 0; mt < 4; mt++)
    cinv[mt] = 1.f / (1e-9f + colsum[b * NN + mB + mt * 16 + q]);
#pragma unroll
  for (int ct = 0; ct < 2; ct++) {
#pragma unroll
    for (int mt = 0; mt < 4; mt++) {
      h4_t hd;
#pragma unroll
      for (int r = 0; r < 4; r++) {
        int c = 32 * w + ct * 16 + g * 4 + r;
        int m = mB + mt * 16 + q;
        float xa = acc[ct][mt][r] * cinv[mt];
        float xd = x[((size_t)b * CC + c) * NN + m] - xa;
        hd[r] = (_Float16)xd;
      }
      int mloc = mt * 16 + q;
      int c0 = 32 * w + ct * 16 + g * 4;
      *(h4_t*)&xdT[(mloc * 256 + c0) ^ ((mloc & 7) << 3)] = hd;
    }
  }
  __syncthreads();
  // t = wt @ x_d + bt (full C contraction from LDS)
  fx4 acct[2][4] = {};
  for (int kt = 0; kt < 8; kt++) {
    h8_t bx[4];
#pragma unroll
    for (int mt = 0; mt < 4; mt++) {
      int m = mt * 16 + q;
      bx[mt] = *(const h8_t*)&xdT[(m * 256 + kt * 32 + g * 8) ^ swzq];
    }
#pragma unroll
    for (int ot = 0; ot < 2; ot++) {
      h8_t a = *(const h8_t*)(wtH + (size_t)(32 * w + ot * 16 + q) * CC + kt * 32 + g * 8);
#pragma unroll
      for (int mt = 0; mt < 4; mt++)
        acct[ot][mt] = MFMA16(a, bx[mt], acct[ot][mt]);
    }
  }
#pragma unroll
  for (int ot = 0; ot < 2; ot++) {
#pragma unroll
    for (int r = 0; r < 4; r++) {
      int o = 32 * w + ot * 16 + g * 4 + r;
      float btv = bt[o];
      float s1 = 0.f, s2 = 0.f;
#pragma unroll
      for (int mt = 0; mt < 4; mt++) {
        float tv = acct[ot][mt][r] + btv;
        th[((size_t)b * CC + o) * NN + mB + mt * 16 + q] = (_Float16)tv;
        s1 += tv;
        s2 += tv * tv;
      }
#pragma unroll
      for (int off = 1; off < 16; off <<= 1) {
        s1 += __shfl_xor(s1, off);
        s2 += __shfl_xor(s2, off);
      }
      if (q == 0) {
        atomicAdd(&bnsum[o], s1);
        atomicAdd(&bnsumsq[o], s2);
      }
    }
  }
}

// ---------------- K5: BN finalize -> scale/shift per channel -------------------
__global__ __launch_bounds__(256) void k5_bnfinal(
    const float* __restrict__ bnsum, const float* __restrict__ bnsumsq,
    const float* __restrict__ gamma, const float* __restrict__ beta,
    float* __restrict__ bnsc, float* __restrict__ bnsh) {
  int c = threadIdx.x;
  float inv = 1.f / (float)(BB * NN);
  float mean = bnsum[c] * inv;
  float var = bnsumsq[c] * inv - mean * mean;
  float sc = gamma[c] * rsqrtf(var + 1e-5f);
  bnsc[c] = sc;
  bnsh[c] = beta[c] - mean * sc;
}

// ---------------- K6: out = x + relu(scale*t + shift) --------------------------
__global__ __launch_bounds__(256) void k6_final(
    const float* __restrict__ x, const _Float16* __restrict__ th,
    const float* __restrict__ bnsc, const float* __restrict__ bnsh,
    float* __restrict__ out) {
  size_t i = (size_t)blockIdx.x * 256 + threadIdx.x;
  size_t base = i * 8;
  int c = (int)((base >> 12) & 255);
  h8_t t8 = *(const h8_t*)(th + base);
  float sc = bnsc[c], sh = bnsh[c];
  fx4 x0 = *(const fx4*)(x + base);
  fx4 x1 = *(const fx4*)(x + base + 4);
  fx4 o0, o1;
#pragma unroll
  for (int j2 = 0; j2 < 4; j2++) {
    o0[j2] = x0[j2] + fmaxf(0.f, sc * (float)t8[j2] + sh);
    o1[j2] = x1[j2] + fmaxf(0.f, sc * (float)t8[j2 + 4] + sh);
  }
  *(fx4*)(out + base) = o0;
  *(fx4*)(out + base + 4) = o1;
}

extern "C" void kernel_launch(void* const* d_in, const int* in_sizes, int n_in,
                              void* d_out, int out_size, void* d_ws, size_t ws_size,
                              hipStream_t stream) {
  const float* x = (const float*)d_in[0];
  const float* wq = (const float*)d_in[1];
  const float* wv = (const float*)d_in[2];
  const float* bv = (const float*)d_in[3];
  const float* wt = (const float*)d_in[4];
  const float* bt = (const float*)d_in[5];
  const float* gamma = (const float*)d_in[6];
  const float* beta = (const float*)d_in[7];
  char* ws = (char*)d_ws;
  _Float16* qh = (_Float16*)(ws + 0);            // 2 MB
  _Float16* vh = (_Float16*)(ws + 2097152);      // 8 MB
  _Float16* xt = (_Float16*)(ws + 10485760);     // 8 MB
  _Float16* wqH = (_Float16*)(ws + 18874368);    // 32 KB
  _Float16* wvH = (_Float16*)(ws + 18907136);    // 128 KB
  _Float16* wtH = (_Float16*)(ws + 19038208);    // 128 KB
  float* rowmax = (float*)(ws + 19169280);       // 64 KB
  float* rowsuminv = (float*)(ws + 19234816);    // 64 KB
  float* colsum = (float*)(ws + 19300352);       // 64 KB
  float* bnsum = (float*)(ws + 19365888);        // 1 KB
  float* bnsumsq = (float*)(ws + 19366912);      // 1 KB
  float* bnsc = (float*)(ws + 19367936);         // 1 KB
  float* bnsh = (float*)(ws + 19368960);         // 1 KB
  _Float16* th = (_Float16*)(ws + 19369984);     // 8 MB  (total ~26.5 MB)

  hipLaunchKernelGGL(k0_prep, dim3(64), dim3(256), 0, stream,
                     wq, wv, wt, wqH, wvH, wtH, bnsum, bnsumsq);
  hipLaunchKernelGGL(k1a_transpose, dim3(128, 8, 4), dim3(256), 0, stream, x, xt);
  hipLaunchKernelGGL(k1b_proj, dim3(512), dim3(256), 0, stream, xt, wqH, wvH, bv, qh, vh);
  hipLaunchKernelGGL(k2_stats, dim3(256), dim3(512), 0, stream, qh, rowmax, rowsuminv);
  hipLaunchKernelGGL(k3_colsum, dim3(256), dim3(512), 0, stream, qh, rowmax, rowsuminv, colsum);
  hipLaunchKernelGGL(k4_main, dim3(256), dim3(512), 0, stream, qh, vh, wtH,
                     rowmax, rowsuminv, colsum, x, bt, th, bnsum, bnsumsq);
  hipLaunchKernelGGL(k5_bnfinal, dim3(1), dim3(256), 0, stream,
                     bnsum, bnsumsq, gamma, beta, bnsc, bnsh);
  hipLaunchKernelGGL(k6_final, dim3(2048), dim3(256), 0, stream,
                     x, th, bnsc, bnsh, (float*)d_out);
}